// Round 16
// baseline (94.142 us; speedup 1.0000x reference)
//
#include <hip/hip_runtime.h>

#define D 256
#define N 2048
#define NB 8
#define ZSTRIDE (257 * 2048)   // per-batch Z_in / out stride

typedef __attribute__((ext_vector_type(8))) short short8;
typedef __attribute__((ext_vector_type(4))) short short4v;
typedef __attribute__((ext_vector_type(4))) float f32x4;

#define MFMA(a, b, c) __builtin_amdgcn_mfma_f32_16x16x32_bf16((a), (b), (c), 0, 0, 0)

#define GLOAD_LDS16(g, s) __builtin_amdgcn_global_load_lds( \
    (const __attribute__((address_space(1))) void*)(g),     \
    (__attribute__((address_space(3))) void*)(s), 16, 0, 0)

// counted-vmcnt wait (T4): N = loads left in flight across the barrier
#define VMCNT(Nstr) asm volatile("s_waitcnt vmcnt(" Nstr ")" ::: "memory")
#define BAR() __builtin_amdgcn_s_barrier()

__device__ __forceinline__ short f2bf(float f) {
    unsigned u = __builtin_bit_cast(unsigned, f);
    u += 0x7fffu + ((u >> 16) & 1u);
    return (short)(u >> 16);
}
__device__ __forceinline__ float bf2f(short s) {
    unsigned u = ((unsigned)(unsigned short)s) << 16;
    return __builtin_bit_cast(float, u);
}

// ---------------------------------------------------------------------------
// K0: G = B_l^T C_l (bf16), Ab = bf16(A_l), Yb = bf16(Y), zero accY
// ---------------------------------------------------------------------------
__global__ __launch_bounds__(256) void prep_small(
    const float* __restrict__ B_l, const float* __restrict__ C_l,
    const float* __restrict__ A_l, const float* __restrict__ Z,
    short* __restrict__ G, short* __restrict__ Ab, short* __restrict__ Yb,
    float* __restrict__ accY, int zeroAcc)
{
    int blk = blockIdx.x, tid = threadIdx.x;
    if (blk < 256) {
        float s = 0.f;
        #pragma unroll 8
        for (int k = 0; k < 256; ++k)
            s += B_l[k * 256 + blk] * C_l[k * 256 + tid];
        G[blk * 256 + tid] = f2bf(s);
    } else if (blk < 320) {
        int base = (blk - 256) * 1024 + tid;
        #pragma unroll
        for (int r = 0; r < 4; ++r) {
            int idx = base + r * 256;
            Ab[idx] = f2bf(A_l[idx]);
        }
    } else if (blk < 336) {
        int base = (blk - 320) * 1024 + tid;
        #pragma unroll
        for (int r = 0; r < 4; ++r) {
            int idx = base + r * 256;          // idx = b*2048 + n
            int b = idx >> 11, n = idx & 2047;
            Yb[idx] = f2bf(Z[(size_t)b * ZSTRIDE + 256 * N + n]);
        }
    } else if (zeroAcc) {
        int i = (blk - 336) * 256 + tid;
        f32x4 z = {0.f, 0.f, 0.f, 0.f};
        *(f32x4*)(accY + (size_t)i * 4) = z;
    }
}

// ---------------------------------------------------------------------------
// K1: Xt[b][n][d] = bf16(X[b][d][n]) (row-major, for prep_gemm2)
//     + Xt2: stage-order tiled [nt(16)][kt(8)][row(128)][32k], pre-XOR'd.
// ---------------------------------------------------------------------------
__global__ __launch_bounds__(256) void transpose_kernel(
    const float* __restrict__ Z, short* __restrict__ Xt, short* __restrict__ Xt2)
{
    typedef __attribute__((ext_vector_type(4))) float f4;
    __shared__ short t[64][68];
    int blk = blockIdx.x;
    int b = blk & 7;
    int dt = (blk >> 3) & 3;
    int nt4 = blk >> 5;
    int d0 = dt * 64, n0 = nt4 * 64;
    const float* ZB = Z + (size_t)b * ZSTRIDE;
    int tid = threadIdx.x;
    #pragma unroll
    for (int k = 0; k < 4; ++k) {
        int f = tid + k * 256;
        int r = f >> 4, c4 = f & 15;
        f4 v = *(const f4*)(ZB + (size_t)(d0 + r) * N + n0 + c4 * 4);
        #pragma unroll
        for (int j = 0; j < 4; ++j) t[r][c4 * 4 + j] = f2bf(v[j]);
    }
    __syncthreads();
    short* XtB = Xt + (size_t)b * (N * D);
    short* Xt2B = Xt2 + (size_t)b * (N * D);
    #pragma unroll
    for (int k = 0; k < 2; ++k) {
        int f = tid + k * 256;
        int n = f >> 3, c8 = f & 7;
        short8 v;
        #pragma unroll
        for (int j = 0; j < 8; ++j) v[j] = t[c8 * 8 + j][n];
        int gn = n0 + n;
        int d = d0 + c8 * 8;
        *(short8*)(XtB + (size_t)gn * D + d) = v;
        // tiled copy (pre-swizzled)
        int nt = gn >> 7, mrow = gn & 127;
        int kt = d >> 5, q = (d & 31) >> 3;
        int slot = q ^ ((mrow >> 1) & 3);
        *(short8*)(Xt2B + (size_t)nt * 32768 + kt * 4096 + mrow * 32 + slot * 8) = v;
    }
}

// ---------------------------------------------------------------------------
// K2: unified prep GEMM, 512 threads / 8 waves, 128x128 tile, BK=64.
//     half 0 output: Wt2 tiled [mt][kt][row][32k] pre-XOR'd (if tiledWt).
// ---------------------------------------------------------------------------
__global__ __launch_bounds__(512, 4) void prep_gemm2(
    const short* __restrict__ Xt, const short* __restrict__ G,
    const short* __restrict__ Ab, short* __restrict__ Wt, short* __restrict__ Px,
    int tiledWt)
{
    __shared__ __align__(16) char smem[65536];
    typedef short TileT[128][64];
    TileT* As = (TileT*)smem;              // As[2]: 32 KB
    TileT* Bs = (TileT*)(smem + 32768);    // Bs[2]: 32 KB

    int blk = blockIdx.x;
    int half = blk >> 8;                   // 0 = Wt, 1 = Px
    int r0 = blk & 255;
    int b = r0 >> 5;
    int idx = r0 & 31;

    const short* Arows;
    const short* Brows;
    int row_base, col_base;
    if (half == 0) {
        row_base = (idx & 15) << 7;        // m
        col_base = (idx >> 4) << 7;        // d
        Arows = Xt + (size_t)b * (N * D);
        Brows = G;
    } else {
        row_base = (idx & 1) << 7;         // d
        col_base = (idx >> 1) << 7;        // n
        Arows = Ab;
        Brows = Xt + (size_t)b * (N * D);
    }

    int tid = threadIdx.x;
    int w = tid >> 6, l = tid & 63;
    int l16 = l & 15, lq = l >> 4;
    int wm = w >> 2, wn = w & 3;           // 2 x 4 quadrants (64 x 32)
    int lrow8 = l >> 3, lc = l & 7;

    auto STAGE = [&](const short* base, int row0g, int kt, TileT* dst) {
        #pragma unroll
        for (int i = 0; i < 2; ++i) {
            int rloc = i * 64 + w * 8;
            int row = rloc + lrow8;
            const char* src = (const char*)(base + (size_t)(row0g + row) * D)
                              + kt * 128 + ((lc ^ (row & 7)) * 16);
            GLOAD_LDS16(src, &(*dst)[rloc][0]);
        }
    };

    f32x4 zero4 = {0.f, 0.f, 0.f, 0.f};
    f32x4 acc[4][2];
    #pragma unroll
    for (int mi = 0; mi < 4; ++mi)
        #pragma unroll
        for (int ni = 0; ni < 2; ++ni) acc[mi][ni] = zero4;

    STAGE(Arows, row_base, 0, &As[0]);
    STAGE(Brows, col_base, 0, &Bs[0]);

    int buf = 0;
    #pragma unroll
    for (int kt = 0; kt < 4; ++kt) {
        if (kt < 3) {
            STAGE(Arows, row_base, kt + 1, &As[buf ^ 1]);
            STAGE(Brows, col_base, kt + 1, &Bs[buf ^ 1]);
            VMCNT("4");
        } else {
            VMCNT("0");
        }
        BAR();
        __builtin_amdgcn_s_setprio(1);
        #pragma unroll
        for (int ks = 0; ks < 2; ++ks) {
            short8 af[4], bf[2];
            #pragma unroll
            for (int mi = 0; mi < 4; ++mi) {
                int r = wm * 64 + mi * 16 + l16;
                af[mi] = *(const short8*)(&As[buf][r][(ks * 32 + lq * 8) ^ ((r & 7) << 3)]);
            }
            #pragma unroll
            for (int ni = 0; ni < 2; ++ni) {
                int r = wn * 32 + ni * 16 + l16;
                bf[ni] = *(const short8*)(&Bs[buf][r][(ks * 32 + lq * 8) ^ ((r & 7) << 3)]);
            }
            #pragma unroll
            for (int mi = 0; mi < 4; ++mi)
                #pragma unroll
                for (int ni = 0; ni < 2; ++ni)
                    acc[mi][ni] = MFMA(af[mi], bf[ni], acc[mi][ni]);
        }
        __builtin_amdgcn_s_setprio(0);
        BAR();
        buf ^= 1;
    }

    short* cq = (short*)smem + (size_t)w * (64 * 40);
    #pragma unroll
    for (int mi = 0; mi < 4; ++mi)
        #pragma unroll
        for (int ni = 0; ni < 2; ++ni)
            #pragma unroll
            for (int rg = 0; rg < 4; ++rg)
                cq[(mi * 16 + lq * 4 + rg) * 40 + ni * 16 + l16] =
                    f2bf(acc[mi][ni][rg]);
    if (half == 0 && tiledWt) {
        // tiled store: Wt2[mt][kt][mrow][slot]
        short* base2 = Wt + (size_t)b * (N * D) + (size_t)(row_base >> 7) * 32768;
        #pragma unroll
        for (int p = 0; p < 4; ++p) {
            int row = p * 16 + (l >> 2), c8 = l & 3;
            short8 v = *(const short8*)(&cq[row * 40 + c8 * 8]);
            int mrow = wm * 64 + row;
            int kt2 = (col_base >> 5) + wn;
            int slot = c8 ^ ((mrow >> 1) & 3);
            *(short8*)(base2 + (size_t)kt2 * 4096 + mrow * 32 + slot * 8) = v;
        }
    } else {
        short* Cout;
        size_t cstride;
        if (half == 0) { Cout = Wt + (size_t)b * (N * D); cstride = D; }
        else           { Cout = Px + (size_t)b * (D * N); cstride = N; }
        #pragma unroll
        for (int p = 0; p < 4; ++p) {
            int row = p * 16 + (l >> 2), c8 = l & 3;
            short8 v = *(const short8*)(&cq[row * 40 + c8 * 8]);
            *(short8*)(Cout + (size_t)(row_base + wm * 64 + row) * cstride +
                       col_base + wn * 32 + c8 * 8) = v;
        }
    }
}

// ---------------------------------------------------------------------------
// K3a: scores GEMM v7 — v6 structure, stage reads from TILED Wt2/Xt2
//      (contiguous 8KB blocks, linear per-lane source, pre-XOR'd).
// ---------------------------------------------------------------------------
__global__ __launch_bounds__(512, 4) void scores_kernel(
    const short* __restrict__ Xt2, const short* __restrict__ Wt2,
    const short* __restrict__ Yb, short* __restrict__ attT,
    float* __restrict__ accY, int bBase, int nbMask, int nbShift)
{
    __shared__ __align__(16) char smem[77824];
    typedef short ATile[128][32];
    typedef short BTile[256][32];
    ATile* As = (ATile*)smem;               // 2 x 8 KB
    BTile* Bs = (BTile*)(smem + 16384);     // 2 x 16 KB
    short* scratch = (short*)(smem + 49152); // 8 waves x 64 x 28 shorts

    int blk = blockIdx.x;
    int b_local = blk & nbMask;
    int idx = blk >> nbShift;          // 0..63
    int m_base = (idx & 15) << 7;      // 16 m-tiles of 128
    int nsup = (idx >> 4) << 9;        // 4 n-strips of 512
    int b = bBase + b_local;

    int tid = threadIdx.x;
    int w = tid >> 6, l = tid & 63;
    int l16 = l & 15, lq = l >> 4;
    int wm = w >> 2, wn = w & 3;       // 2m x 4n waves, each 64x64

    const short* Wt2B = Wt2 + (size_t)b * (N * D) + (size_t)(m_base >> 7) * 32768;
    const short* Xt2B = Xt2 + (size_t)b * (N * D);
    const short* YbB = Yb + (size_t)b * N;
    float* accYB = accY + (size_t)b * N;
    short* attTB = attT + (size_t)b_local * N * N;
    int nt0base = nsup >> 7;

    auto STAGE_A = [&](int kt, int bi) {
        const char* src = (const char*)Wt2B + kt * 8192 + w * 1024 + l * 16;
        GLOAD_LDS16(src, &As[bi][w * 16][0]);
    };
    auto STAGE_B = [&](int s, int kt, int bi) {
        #pragma unroll
        for (int i = 0; i < 2; ++i) {
            const char* src = (const char*)Xt2B +
                (size_t)(nt0base + s * 2 + i) * 65536 + kt * 8192 + w * 1024 + l * 16;
            GLOAD_LDS16(src, &Bs[bi][i * 128 + w * 16][0]);
        }
    };

    f32x4 zero4 = {0.f, 0.f, 0.f, 0.f};
    f32x4 acc[4][4];
    #pragma unroll
    for (int mi = 0; mi < 4; ++mi)
        #pragma unroll
        for (int ni = 0; ni < 4; ++ni) acc[mi][ni] = zero4;

    STAGE_A(0, 0);
    STAGE_B(0, 0, 0);

    for (int t = 0; t < 16; ++t) {
        int kt = t & 7;
        int s = t >> 3;
        int buf = t & 1;
        if (t < 15) {
            int t1 = t + 1;
            STAGE_A(t1 & 7, t1 & 1);
            STAGE_B(t1 >> 3, t1 & 7, t1 & 1);
            VMCNT("3");
        } else {
            VMCNT("0");
        }
        BAR();
        __builtin_amdgcn_s_setprio(1);
        {
            short8 af[4], bf[4];
            #pragma unroll
            for (int mi = 0; mi < 4; ++mi) {
                int r = wm * 64 + mi * 16 + l16;
                af[mi] = *(const short8*)(&As[buf][r][(lq ^ ((r >> 1) & 3)) * 8]);
            }
            #pragma unroll
            for (int ni = 0; ni < 4; ++ni) {
                int r = wn * 64 + ni * 16 + l16;
                bf[ni] = *(const short8*)(&Bs[buf][r][(lq ^ ((r >> 1) & 3)) * 8]);
            }
            #pragma unroll
            for (int mi = 0; mi < 4; ++mi)
                #pragma unroll
                for (int ni = 0; ni < 4; ++ni)
                    acc[mi][ni] = MFMA(af[mi], bf[ni], acc[mi][ni]);
        }
        __builtin_amdgcn_s_setprio(0);
        BAR();

        if (kt == 7) {
            int n_base = nsup + s * 256;
            bool corner = (m_base == 1920) && (n_base == 1792);
            #pragma unroll
            for (int mi = 0; mi < 4; ++mi)
                #pragma unroll
                for (int ni = 0; ni < 4; ++ni)
                    #pragma unroll
                    for (int rg = 0; rg < 4; ++rg) {
                        float v = acc[mi][ni][rg];
                        v = v > 0.f ? v : 0.f;
                        if (corner) {
                            int gm = m_base + wm * 64 + mi * 16 + lq * 4 + rg;
                            int gn = n_base + wn * 64 + ni * 16 + l16;
                            if (gm == N - 1 && gn == N - 1) v = 0.f;
                        }
                        acc[mi][ni][rg] = v;
                    }
            {
                float yv[4];
                #pragma unroll
                for (int ni = 0; ni < 4; ++ni)
                    yv[ni] = bf2f(YbB[n_base + wn * 64 + ni * 16 + l16]);
                #pragma unroll
                for (int mi = 0; mi < 4; ++mi)
                    #pragma unroll
                    for (int rg = 0; rg < 4; ++rg) {
                        float sY = acc[mi][0][rg] * yv[0] + acc[mi][1][rg] * yv[1]
                                 + acc[mi][2][rg] * yv[2] + acc[mi][3][rg] * yv[3];
                        sY += __shfl_xor(sY, 1);
                        sY += __shfl_xor(sY, 2);
                        sY += __shfl_xor(sY, 4);
                        sY += __shfl_xor(sY, 8);
                        if (l16 == 0)
                            atomicAdd(&accYB[m_base + wm * 64 + mi * 16 + lq * 4 + rg], sY);
                    }
            }
            {
                short* sq = scratch + (size_t)w * (64 * 28);
                #pragma unroll
                for (int h = 0; h < 4; ++h) {
                    #pragma unroll
                    for (int mi = 0; mi < 4; ++mi)
                        #pragma unroll
                        for (int rg = 0; rg < 4; ++rg)
                            sq[(mi * 16 + lq * 4 + rg) * 28 + l16] =
                                f2bf(acc[mi][h][rg]);
                    #pragma unroll
                    for (int p = 0; p < 2; ++p) {
                        int row = p * 32 + (l >> 1), c8 = l & 1;
                        short8 v = *(const short8*)(&sq[row * 28 + c8 * 8]);
                        *(short8*)(attTB + (size_t)(m_base + wm * 64 + row) * N +
                                   n_base + wn * 64 + h * 16 + c8 * 8) = v;
                    }
                }
            }
            #pragma unroll
            for (int mi = 0; mi < 4; ++mi)
                #pragma unroll
                for (int ni = 0; ni < 4; ++ni) acc[mi][ni] = zero4;
        }
    }
}

// ---------------------------------------------------------------------------
// K3b: PV GEMM, 512 threads / 8 waves. Block = 64d x 128m, K=2048 (BK=64).
//      Counted-vmcnt schedule. d_base==0 blocks also emit Y_out.
// ---------------------------------------------------------------------------
__global__ __launch_bounds__(512, 4) void pv_kernel(
    const float* __restrict__ Z, const short* __restrict__ Px,
    const short* __restrict__ attT, const float* __restrict__ accY,
    const float* __restrict__ r_l, float* __restrict__ out,
    int bBase, int nbMask, int nbShift)
{
    __shared__ __align__(16) char smem[49152];
    typedef short ATile[64][64];
    typedef short BTile[128][64];
    ATile* As = (ATile*)smem;              // 2 x 8 KB
    BTile* Bs = (BTile*)(smem + 16384);    // 2 x 16 KB

    int blk = blockIdx.x;
    int b_local = blk & nbMask;
    int idx = blk >> nbShift;
    int d_base = (idx & 3) << 6;
    int m_base = (idx >> 2) << 7;
    int b = bBase + b_local;

    int tid = threadIdx.x;
    int w = tid >> 6, l = tid & 63;
    int l16 = l & 15, lq = l >> 4;
    int wd = w >> 2, wm = w & 3;           // 2 x 4 quadrants (32d x 32m)
    int lrow8 = l >> 3, lc = l & 7;

    const short* PxB = Px + (size_t)b * (D * N);
    const short* attTB = attT + (size_t)b_local * N * N;

    auto STAGE_A = [&](int kt, ATile* dst) {
        int rloc = w * 8;
        int row = rloc + lrow8;
        const char* src = (const char*)(PxB + (size_t)(d_base + row) * N)
                          + kt * 128 + ((lc ^ (row & 7)) * 16);
        GLOAD_LDS16(src, &(*dst)[rloc][0]);
    };
    auto STAGE_B = [&](int kt, BTile* dst) {
        #pragma unroll
        for (int i = 0; i < 2; ++i) {
            int rloc = i * 64 + w * 8;
            int row = rloc + lrow8;
            const char* src = (const char*)(attTB + (size_t)(m_base + row) * N)
                              + kt * 128 + ((lc ^ (row & 7)) * 16);
            GLOAD_LDS16(src, &(*dst)[rloc][0]);
        }
    };

    f32x4 zero4 = {0.f, 0.f, 0.f, 0.f};
    f32x4 acc[2][2];
    #pragma unroll
    for (int di = 0; di < 2; ++di)
        #pragma unroll
        for (int mj = 0; mj < 2; ++mj) acc[di][mj] = zero4;

    STAGE_A(0, &As[0]);
    STAGE_B(0, &Bs[0]);

    int buf = 0;
    for (int kt = 0; kt < 32; ++kt) {
        if (kt < 31) {
            STAGE_A(kt + 1, &As[buf ^ 1]);
            STAGE_B(kt + 1, &Bs[buf ^ 1]);
            VMCNT("3");
        } else {
            VMCNT("0");
        }
        BAR();
        __builtin_amdgcn_s_setprio(1);
        #pragma unroll
        for (int ks = 0; ks < 2; ++ks) {
            short8 af[2], bf[2];
            #pragma unroll
            for (int di = 0; di < 2; ++di) {
                int r = wd * 32 + di * 16 + l16;
                af[di] = *(const short8*)(&As[buf][r][(ks * 32 + lq * 8) ^ ((r & 7) << 3)]);
            }
            #pragma unroll
            for (int mj = 0; mj < 2; ++mj) {
                int r = wm * 32 + mj * 16 + l16;
                bf[mj] = *(const short8*)(&Bs[buf][r][(ks * 32 + lq * 8) ^ ((r & 7) << 3)]);
            }
            #pragma unroll
            for (int di = 0; di < 2; ++di)
                #pragma unroll
                for (int mj = 0; mj < 2; ++mj)
                    acc[di][mj] = MFMA(af[di], bf[mj], acc[di][mj]);
        }
        __builtin_amdgcn_s_setprio(0);
        BAR();
        buf ^= 1;
    }

    #pragma unroll
    for (int di = 0; di < 2; ++di)
        #pragma unroll
        for (int mj = 0; mj < 2; ++mj)
            #pragma unroll
            for (int rg = 0; rg < 4; ++rg) {
                int dd = d_base + wd * 32 + di * 16 + lq * 4 + rg;
                int mm = m_base + wm * 32 + mj * 16 + l16;
                size_t off = (size_t)b * ZSTRIDE + (size_t)dd * N + mm;
                out[off] = Z[off] + acc[di][mj][rg];
            }

    if (d_base == 0 && tid < 128) {
        int mm = m_base + tid;
        size_t off = (size_t)b * ZSTRIDE + (size_t)256 * N + mm;
        out[off] = Z[off] + r_l[0] * accY[(size_t)b * N + mm];
    }
}

// ---------------------------------------------------------------------------
// Fallback fused kernel (round-4, known-good) if ws too small for attT
// (prep_gemm2 writes row-major Wt in that case: tiledWt=0)
// ---------------------------------------------------------------------------
__global__ __launch_bounds__(512, 4) void fused_kernel(
    const float* __restrict__ Z, const short* __restrict__ Xt,
    const short* __restrict__ Wt, const short* __restrict__ Px,
    const short* __restrict__ Yb, const float* __restrict__ r_l,
    float* __restrict__ out)
{
    __shared__ __align__(16) short xtsA[32][256];
    __shared__ __align__(16) short xtsB[32][256];
    __shared__ __align__(16) short attA[64][36];
    __shared__ __align__(16) short attB[64][36];

    int blk = blockIdx.x;
    int b = blk & 7;
    int m_base = (blk >> 3) << 6;
    int tid = threadIdx.x;
    int w = tid >> 6, l = tid & 63;
    int l16 = l & 15, lq = l >> 4;

    const short* XtB = Xt + (size_t)b * (N * D);
    const short* WtB = Wt + (size_t)b * (N * D);
    const short* PxB = Px + (size_t)b * (D * N);
    const short* YbB = Yb + b * N;

    int mi = w >> 1;
    int nj = w & 1;

    short8 a_wt[8];
    {
        const short* ap = WtB + (size_t)(m_base + 16 * mi + l16) * D + lq * 8;
        #pragma unroll
        for (int ks = 0; ks < 8; ++ks)
            a_wt[ks] = *(const short8*)(ap + ks * 32);
    }

    f32x4 zero4 = {0.f, 0.f, 0.f, 0.f};
    f32x4 accX[2][4];
    #pragma unroll
    for (int di = 0; di < 2; ++di)
        #pragma unroll
        for (int mj = 0; mj < 4; ++mj) accX[di][mj] = zero4;

    float accY = 0.f;
    int ym = tid >> 3, yseg = tid & 7;

    auto STAGE = [&](int it, short (*dst)[256]) {
        #pragma unroll
        for (int r = 0; r < 2; ++r) {
            int row  = r * 16 + 2 * w + (l >> 5);
            int colb = ((l & 31) * 16) ^ ((row & 7) << 4);
            const char* src = (const char*)(XtB + (size_t)(it * 32 + row) * D) + colb;
            GLOAD_LDS16(src, &dst[r * 16 + 2 * w][0]);
        }
    };

    auto BODY = [&](int it, short (*xrd)[256], short (*xst)[256], short (*atw)[36]) {
        int n_base = it * 32;
        if (it + 1 < 64) STAGE(it + 1, xst);
        short8 px[2];
        #pragma unroll
        for (int di = 0; di < 2; ++di)
            px[di] = *(const short8*)(PxB + (size_t)(32 * w + 16 * di + l16) * N +
                                      n_base + lq * 8);
        short4v yv = *(const short4v*)(YbB + n_base + yseg * 4);
        f32x4 sa = zero4;
        #pragma unroll
        for (int ks = 0; ks < 8; ++ks) {
            int colsh = (ks * 32 + lq * 8) ^ ((l16 & 7) << 3);
            short8 xb = *(const short8*)(&xrd[16 * nj + l16][colsh]);
            sa = MFMA(a_wt[ks], xb, sa);
        }
        {
            int nn = 16 * nj + l16;
            #pragma unroll
            for (int rg = 0; rg < 4; ++rg) {
                int mm = 16 * mi + lq * 4 + rg;
                float v = sa[rg] > 0.f ? sa[rg] : 0.f;
                if ((m_base + mm == N - 1) && (n_base + nn == N - 1)) v = 0.f;
                atw[mm][nn] = f2bf(v);
            }
        }
        __syncthreads();
        #pragma unroll
        for (int mj = 0; mj < 4; ++mj) {
            short8 bfr = *(const short8*)(&atw[16 * mj + l16][lq * 8]);
            #pragma unroll
            for (int di = 0; di < 2; ++di)
                accX[di][mj] = MFMA(px[di], bfr, accX[di][mj]);
        }
        {
            short4v av = *(const short4v*)(&atw[ym][yseg * 4]);
            #pragma unroll
            for (int j = 0; j < 4; ++j)
                accY += bf2f(av[j]) * bf2f(yv[j]);
        }
    };

    STAGE(0, xtsA);
    __syncthreads();
    for (int it2 = 0; it2 < 32; ++it2) {
        BODY(2 * it2,     xtsA, xtsB, attA);
        BODY(2 * it2 + 1, xtsB, xtsA, attB);
    }

    #pragma unroll
    for (int di = 0; di < 2; ++di)
        #pragma unroll
        for (int mj = 0; mj < 4; ++mj)
            #pragma unroll
            for (int rg = 0; rg < 4; ++rg) {
                int dd = 32 * w + 16 * di + lq * 4 + rg;
                int mm = m_base + 16 * mj + l16;
                size_t off = (size_t)b * ZSTRIDE + (size_t)dd * N + mm;
                out[off] = Z[off] + accX[di][mj][rg];
            }
    accY += __shfl_xor(accY, 1);
    accY += __shfl_xor(accY, 2);
    accY += __shfl_xor(accY, 4);
    if (yseg == 0) {
        float r = r_l[0];
        int mm = m_base + ym;
        size_t off = (size_t)b * ZSTRIDE + (size_t)256 * N + mm;
        out[off] = Z[off] + r * accY;
    }
}

// ---------------------------------------------------------------------------
extern "C" void kernel_launch(void* const* d_in, const int* in_sizes, int n_in,
                              void* d_out, int out_size, void* d_ws, size_t ws_size,
                              hipStream_t stream) {
    const float* Z   = (const float*)d_in[0];
    const float* A_l = (const float*)d_in[1];
    const float* r_l = (const float*)d_in[2];
    const float* B_l = (const float*)d_in[3];
    const float* C_l = (const float*)d_in[4];
    float* out = (float*)d_out;

    char* ws = (char*)d_ws;
    short* G    = (short*)(ws);                  // 128 KB
    short* Ab   = (short*)(ws + 131072);         // 128 KB
    short* Xt   = (short*)(ws + 262144);         // 8 MB
    short* Wt   = (short*)(ws + 8650752);        // 8 MB (tiled Wt2 when decomposed)
    short* Px   = (short*)(ws + 17039360);       // 8 MB
    short* Yb   = (short*)(ws + 25427968);       // 32 KB
    float* accY = (float*)(ws + 25460736);       // 64 KB
    short* Xt2  = (short*)(ws + 25526272);       // 8 MB (tiled Xt)
    short* attT = (short*)(ws + 33914880);       // NBCH x 8 MB

    const size_t baseNeed = 33914880;
    const size_t attSz = (size_t)N * N * 2;      // 8 MB per batch
    int NBCH = 8, nbShift = 3;
    while (NBCH > 1 && baseNeed + (size_t)NBCH * attSz > ws_size) { NBCH >>= 1; --nbShift; }
    bool decomposed = (baseNeed + (size_t)NBCH * attSz <= ws_size);

    prep_small<<<352, 256, 0, stream>>>(B_l, C_l, A_l, Z, G, Ab, Yb,
                                        accY, decomposed ? 1 : 0);
    transpose_kernel<<<1024, 256, 0, stream>>>(Z, Xt, Xt2);
    prep_gemm2<<<512, 512, 0, stream>>>(Xt, G, Ab, Wt, Px, decomposed ? 1 : 0);

    if (decomposed) {
        int nbMask = NBCH - 1;
        for (int c = 0; c < NB / NBCH; ++c) {
            int bBase = c * NBCH;
            scores_kernel<<<NBCH * 64, 512, 0, stream>>>(
                Xt2, Wt, Yb, attT, accY, bBase, nbMask, nbShift);
            pv_kernel<<<NBCH * 64, 512, 0, stream>>>(
                Z, Px, attT, accY, r_l, out, bBase, nbMask, nbShift);
        }
    } else {
        fused_kernel<<<256, 512, 0, stream>>>(Z, Xt, Wt, Px, Yb, r_l, out);
    }
}

// Round 17
// 86.373 us; speedup vs baseline: 1.0899x; 1.0899x over previous
//
#include <hip/hip_runtime.h>

#define D 256
#define N 2048
#define NB 8
#define ZSTRIDE (257 * 2048)   // per-batch Z_in / out stride

typedef __attribute__((ext_vector_type(8))) short short8;
typedef __attribute__((ext_vector_type(4))) short short4v;
typedef __attribute__((ext_vector_type(4))) float f32x4;

#define MFMA(a, b, c) __builtin_amdgcn_mfma_f32_16x16x32_bf16((a), (b), (c), 0, 0, 0)

#define GLOAD_LDS16(g, s) __builtin_amdgcn_global_load_lds( \
    (const __attribute__((address_space(1))) void*)(g),     \
    (__attribute__((address_space(3))) void*)(s), 16, 0, 0)

// counted-vmcnt wait (T4): N = loads left in flight across the barrier
#define VMCNT(Nstr) asm volatile("s_waitcnt vmcnt(" Nstr ")" ::: "memory")
#define BAR() __builtin_amdgcn_s_barrier()

__device__ __forceinline__ short f2bf(float f) {
    unsigned u = __builtin_bit_cast(unsigned, f);
    u += 0x7fffu + ((u >> 16) & 1u);
    return (short)(u >> 16);
}
__device__ __forceinline__ float bf2f(short s) {
    unsigned u = ((unsigned)(unsigned short)s) << 16;
    return __builtin_bit_cast(float, u);
}

// ---------------------------------------------------------------------------
// K0 (front): merged prep_small + transpose.
//   blk <  352 : G = B_l^T C_l, Ab, Yb, zero accY   (round-13 layout)
//   blk >= 352 : Xt[b][n][d] = bf16(X[b][d][n])     (1024 blocks)
// ---------------------------------------------------------------------------
__global__ __launch_bounds__(256) void front_kernel(
    const float* __restrict__ B_l, const float* __restrict__ C_l,
    const float* __restrict__ A_l, const float* __restrict__ Z,
    short* __restrict__ G, short* __restrict__ Ab, short* __restrict__ Yb,
    float* __restrict__ accY, short* __restrict__ Xt, int zeroAcc)
{
    typedef __attribute__((ext_vector_type(4))) float f4;
    __shared__ short t[64][68];
    int blk = blockIdx.x, tid = threadIdx.x;
    if (blk < 352) {
        if (blk < 256) {
            float s = 0.f;
            #pragma unroll 8
            for (int k = 0; k < 256; ++k)
                s += B_l[k * 256 + blk] * C_l[k * 256 + tid];
            G[blk * 256 + tid] = f2bf(s);
        } else if (blk < 320) {
            int base = (blk - 256) * 1024 + tid;
            #pragma unroll
            for (int r = 0; r < 4; ++r) {
                int idx = base + r * 256;
                Ab[idx] = f2bf(A_l[idx]);
            }
        } else if (blk < 336) {
            int base = (blk - 320) * 1024 + tid;
            #pragma unroll
            for (int r = 0; r < 4; ++r) {
                int idx = base + r * 256;          // idx = b*2048 + n
                int b = idx >> 11, n = idx & 2047;
                Yb[idx] = f2bf(Z[(size_t)b * ZSTRIDE + 256 * N + n]);
            }
        } else if (zeroAcc) {
            int i = (blk - 336) * 256 + tid;
            f32x4 z = {0.f, 0.f, 0.f, 0.f};
            *(f32x4*)(accY + (size_t)i * 4) = z;
        }
        return;
    }
    // ---- transpose part
    int tblk = blk - 352;
    int b = tblk & 7;
    int dt = (tblk >> 3) & 3;
    int nt = tblk >> 5;
    int d0 = dt * 64, n0 = nt * 64;
    const float* ZB = Z + (size_t)b * ZSTRIDE;
    #pragma unroll
    for (int k = 0; k < 4; ++k) {
        int f = tid + k * 256;
        int r = f >> 4, c4 = f & 15;
        f4 v = *(const f4*)(ZB + (size_t)(d0 + r) * N + n0 + c4 * 4);
        #pragma unroll
        for (int j = 0; j < 4; ++j) t[r][c4 * 4 + j] = f2bf(v[j]);
    }
    __syncthreads();
    short* XtB = Xt + (size_t)b * (N * D);
    #pragma unroll
    for (int k = 0; k < 2; ++k) {
        int f = tid + k * 256;
        int n = f >> 3, c8 = f & 7;
        short8 v;
        #pragma unroll
        for (int j = 0; j < 8; ++j) v[j] = t[c8 * 8 + j][n];
        *(short8*)(XtB + (size_t)(n0 + n) * D + d0 + c8 * 8) = v;
    }
}

// ---------------------------------------------------------------------------
// K2: unified prep GEMM, 512 threads / 8 waves, 128x128 tile, BK=64.
//     Counted-vmcnt schedule: 4 loads/iter in flight, 2 barriers/iter.
// ---------------------------------------------------------------------------
__global__ __launch_bounds__(512, 4) void prep_gemm2(
    const short* __restrict__ Xt, const short* __restrict__ G,
    const short* __restrict__ Ab, short* __restrict__ Wt, short* __restrict__ Px)
{
    __shared__ __align__(16) char smem[65536];
    typedef short TileT[128][64];
    TileT* As = (TileT*)smem;              // As[2]: 32 KB
    TileT* Bs = (TileT*)(smem + 32768);    // Bs[2]: 32 KB

    int blk = blockIdx.x;
    int half = blk >> 8;                   // 0 = Wt, 1 = Px
    int r0 = blk & 255;
    int b = r0 >> 5;
    int idx = r0 & 31;

    const short* Arows;
    const short* Brows;
    short* Cout;
    size_t cstride;
    int row_base, col_base;
    if (half == 0) {
        row_base = (idx & 15) << 7;        // m
        col_base = (idx >> 4) << 7;        // d
        Arows = Xt + (size_t)b * (N * D);
        Brows = G;
        Cout  = Wt + (size_t)b * (N * D);
        cstride = D;
    } else {
        row_base = (idx & 1) << 7;         // d
        col_base = (idx >> 1) << 7;        // n
        Arows = Ab;
        Brows = Xt + (size_t)b * (N * D);
        Cout  = Px + (size_t)b * (D * N);
        cstride = N;
    }

    int tid = threadIdx.x;
    int w = tid >> 6, l = tid & 63;
    int l16 = l & 15, lq = l >> 4;
    int wm = w >> 2, wn = w & 3;           // 2 x 4 quadrants (64 x 32)
    int lrow8 = l >> 3, lc = l & 7;

    auto STAGE = [&](const short* base, int row0g, int kt, TileT* dst) {
        #pragma unroll
        for (int i = 0; i < 2; ++i) {
            int rloc = i * 64 + w * 8;
            int row = rloc + lrow8;
            const char* src = (const char*)(base + (size_t)(row0g + row) * D)
                              + kt * 128 + ((lc ^ (row & 7)) * 16);
            GLOAD_LDS16(src, &(*dst)[rloc][0]);
        }
    };

    f32x4 zero4 = {0.f, 0.f, 0.f, 0.f};
    f32x4 acc[4][2];
    #pragma unroll
    for (int mi = 0; mi < 4; ++mi)
        #pragma unroll
        for (int ni = 0; ni < 2; ++ni) acc[mi][ni] = zero4;

    STAGE(Arows, row_base, 0, &As[0]);
    STAGE(Brows, col_base, 0, &Bs[0]);

    int buf = 0;
    #pragma unroll
    for (int kt = 0; kt < 4; ++kt) {
        if (kt < 3) {
            STAGE(Arows, row_base, kt + 1, &As[buf ^ 1]);
            STAGE(Brows, col_base, kt + 1, &Bs[buf ^ 1]);
            VMCNT("4");
        } else {
            VMCNT("0");
        }
        BAR();
        __builtin_amdgcn_s_setprio(1);
        #pragma unroll
        for (int ks = 0; ks < 2; ++ks) {
            short8 af[4], bf[2];
            #pragma unroll
            for (int mi = 0; mi < 4; ++mi) {
                int r = wm * 64 + mi * 16 + l16;
                af[mi] = *(const short8*)(&As[buf][r][(ks * 32 + lq * 8) ^ ((r & 7) << 3)]);
            }
            #pragma unroll
            for (int ni = 0; ni < 2; ++ni) {
                int r = wn * 32 + ni * 16 + l16;
                bf[ni] = *(const short8*)(&Bs[buf][r][(ks * 32 + lq * 8) ^ ((r & 7) << 3)]);
            }
            #pragma unroll
            for (int mi = 0; mi < 4; ++mi)
                #pragma unroll
                for (int ni = 0; ni < 2; ++ni)
                    acc[mi][ni] = MFMA(af[mi], bf[ni], acc[mi][ni]);
        }
        __builtin_amdgcn_s_setprio(0);
        BAR();
        buf ^= 1;
    }

    short* cq = (short*)smem + (size_t)w * (64 * 40);
    #pragma unroll
    for (int mi = 0; mi < 4; ++mi)
        #pragma unroll
        for (int ni = 0; ni < 2; ++ni)
            #pragma unroll
            for (int rg = 0; rg < 4; ++rg)
                cq[(mi * 16 + lq * 4 + rg) * 40 + ni * 16 + l16] =
                    f2bf(acc[mi][ni][rg]);
    #pragma unroll
    for (int p = 0; p < 4; ++p) {
        int row = p * 16 + (l >> 2), c8 = l & 3;
        short8 v = *(const short8*)(&cq[row * 40 + c8 * 8]);
        *(short8*)(Cout + (size_t)(row_base + wm * 64 + row) * cstride +
                   col_base + wn * 32 + c8 * 8) = v;
    }
}

// ---------------------------------------------------------------------------
// K3a: scores GEMM v5 (round-14 best) — BK=32, block = 128m x 256n,
//      K=256 -> 8 kt iters, counted vmcnt(3), 2 barriers/iter, setprio.
// ---------------------------------------------------------------------------
__global__ __launch_bounds__(512, 4) void scores_kernel(
    const short* __restrict__ Xt, const short* __restrict__ Wt,
    const short* __restrict__ Yb, short* __restrict__ attT,
    float* __restrict__ accY, int bBase, int nbMask, int nbShift)
{
    __shared__ __align__(16) char smem[49152];
    typedef short ATile[128][32];
    typedef short BTile[256][32];
    ATile* As = (ATile*)smem;               // 2 x 8 KB
    BTile* Bs = (BTile*)(smem + 16384);     // 2 x 16 KB

    int blk = blockIdx.x;
    int b_local = blk & nbMask;
    int idx = blk >> nbShift;          // 0..127
    int m_base = (idx & 15) << 7;      // 16 m-tiles of 128
    int n_base = (idx >> 4) << 8;      // 8 n-tiles of 256
    int b = bBase + b_local;

    int tid = threadIdx.x;
    int w = tid >> 6, l = tid & 63;
    int l16 = l & 15, lq = l >> 4;
    int wm = w >> 2, wn = w & 3;       // 2m x 4n waves, each 64x64
    int lr4 = l >> 2, lc4 = l & 3;

    const short* WtB = Wt + (size_t)b * (N * D);
    const short* XtB = Xt + (size_t)b * (N * D);
    const short* YbB = Yb + (size_t)b * N;
    float* accYB = accY + (size_t)b * N;
    short* attTB = attT + (size_t)b_local * N * N;

    auto STAGE_A = [&](int kt, int bi) {
        int row = w * 16 + lr4;
        const char* src = (const char*)(WtB + (size_t)(m_base + row) * D)
                          + kt * 64 + ((lc4 ^ ((row >> 1) & 3)) * 16);
        GLOAD_LDS16(src, &As[bi][w * 16][0]);
    };
    auto STAGE_B = [&](int kt, int bi) {
        #pragma unroll
        for (int i = 0; i < 2; ++i) {
            int row = i * 128 + w * 16 + lr4;
            const char* src = (const char*)(XtB + (size_t)(n_base + row) * D)
                              + kt * 64 + ((lc4 ^ ((row >> 1) & 3)) * 16);
            GLOAD_LDS16(src, &Bs[bi][i * 128 + w * 16][0]);
        }
    };

    f32x4 zero4 = {0.f, 0.f, 0.f, 0.f};
    f32x4 acc[4][4];
    #pragma unroll
    for (int mi = 0; mi < 4; ++mi)
        #pragma unroll
        for (int ni = 0; ni < 4; ++ni) acc[mi][ni] = zero4;

    STAGE_A(0, 0);
    STAGE_B(0, 0);

    #pragma unroll
    for (int kt = 0; kt < 8; ++kt) {
        if (kt < 7) {
            STAGE_A(kt + 1, (kt + 1) & 1);
            STAGE_B(kt + 1, (kt + 1) & 1);
            VMCNT("3");            // stage(kt) landed; stage(kt+1) in flight
        } else {
            VMCNT("0");
        }
        BAR();                     // all waves' stage(kt) visible
        __builtin_amdgcn_s_setprio(1);
        short8 af[4], bf[4];
        #pragma unroll
        for (int mi = 0; mi < 4; ++mi) {
            int r = wm * 64 + mi * 16 + l16;
            af[mi] = *(const short8*)(&As[kt & 1][r][(lq ^ ((r >> 1) & 3)) * 8]);
        }
        #pragma unroll
        for (int ni = 0; ni < 4; ++ni) {
            int r = wn * 64 + ni * 16 + l16;
            bf[ni] = *(const short8*)(&Bs[kt & 1][r][(lq ^ ((r >> 1) & 3)) * 8]);
        }
        #pragma unroll
        for (int mi = 0; mi < 4; ++mi)
            #pragma unroll
            for (int ni = 0; ni < 4; ++ni)
                acc[mi][ni] = MFMA(af[mi], bf[ni], acc[mi][ni]);
        __builtin_amdgcn_s_setprio(0);
        BAR();
    }

    // ---- relu + corner zero (in regs)
    bool corner = (m_base == 1920) && (n_base == 1792);
    #pragma unroll
    for (int mi = 0; mi < 4; ++mi)
        #pragma unroll
        for (int ni = 0; ni < 4; ++ni)
            #pragma unroll
            for (int rg = 0; rg < 4; ++rg) {
                float v = acc[mi][ni][rg];
                v = v > 0.f ? v : 0.f;
                if (corner) {
                    int gm = m_base + wm * 64 + mi * 16 + lq * 4 + rg;
                    int gn = n_base + wn * 64 + ni * 16 + l16;
                    if (gm == N - 1 && gn == N - 1) v = 0.f;
                }
                acc[mi][ni][rg] = v;
            }

    // ---- Y partials
    {
        float yv[4];
        #pragma unroll
        for (int ni = 0; ni < 4; ++ni)
            yv[ni] = bf2f(YbB[n_base + wn * 64 + ni * 16 + l16]);
        #pragma unroll
        for (int mi = 0; mi < 4; ++mi)
            #pragma unroll
            for (int rg = 0; rg < 4; ++rg) {
                float s = acc[mi][0][rg] * yv[0] + acc[mi][1][rg] * yv[1]
                        + acc[mi][2][rg] * yv[2] + acc[mi][3][rg] * yv[3];
                s += __shfl_xor(s, 1);
                s += __shfl_xor(s, 2);
                s += __shfl_xor(s, 4);
                s += __shfl_xor(s, 8);
                if (l16 == 0)
                    atomicAdd(&accYB[m_base + wm * 64 + mi * 16 + lq * 4 + rg], s);
            }
    }

    // ---- repack 64x64 quadrant in two 64x32 passes via per-wave scratch
    //      (overlays staging LDS; safe: loop ended with a full barrier)
    {
        short* sq = (short*)smem + (size_t)w * (64 * 40);  // 5 KB/wave
        #pragma unroll
        for (int h = 0; h < 2; ++h) {
            #pragma unroll
            for (int mi = 0; mi < 4; ++mi)
                #pragma unroll
                for (int nih = 0; nih < 2; ++nih)
                    #pragma unroll
                    for (int rg = 0; rg < 4; ++rg)
                        sq[(mi * 16 + lq * 4 + rg) * 40 + nih * 16 + l16] =
                            f2bf(acc[mi][h * 2 + nih][rg]);
            #pragma unroll
            for (int p = 0; p < 4; ++p) {
                int row = p * 16 + lr4, c8 = lc4;
                short8 v = *(const short8*)(&sq[row * 40 + c8 * 8]);
                *(short8*)(attTB + (size_t)(m_base + wm * 64 + row) * N +
                           n_base + wn * 64 + h * 32 + c8 * 8) = v;
            }
        }
    }
}

// ---------------------------------------------------------------------------
// K3b: PV GEMM, 512 threads / 8 waves. Block = 64d x 128m, K=2048 (BK=64).
//      Counted-vmcnt schedule. d_base==0 blocks also emit Y_out (fused).
// ---------------------------------------------------------------------------
__global__ __launch_bounds__(512, 4) void pv_kernel(
    const float* __restrict__ Z, const short* __restrict__ Px,
    const short* __restrict__ attT, const float* __restrict__ accY,
    const float* __restrict__ r_l, float* __restrict__ out,
    int bBase, int nbMask, int nbShift)
{
    __shared__ __align__(16) char smem[49152];
    typedef short ATile[64][64];
    typedef short BTile[128][64];
    ATile* As = (ATile*)smem;              // 2 x 8 KB
    BTile* Bs = (BTile*)(smem + 16384);    // 2 x 16 KB

    int blk = blockIdx.x;
    int b_local = blk & nbMask;
    int idx = blk >> nbShift;
    int d_base = (idx & 3) << 6;
    int m_base = (idx >> 2) << 7;
    int b = bBase + b_local;

    int tid = threadIdx.x;
    int w = tid >> 6, l = tid & 63;
    int l16 = l & 15, lq = l >> 4;
    int wd = w >> 2, wm = w & 3;           // 2 x 4 quadrants (32d x 32m)
    int lrow8 = l >> 3, lc = l & 7;

    const short* PxB = Px + (size_t)b * (D * N);
    const short* attTB = attT + (size_t)b_local * N * N;

    auto STAGE_A = [&](int kt, ATile* dst) {
        int rloc = w * 8;
        int row = rloc + lrow8;
        const char* src = (const char*)(PxB + (size_t)(d_base + row) * N)
                          + kt * 128 + ((lc ^ (row & 7)) * 16);
        GLOAD_LDS16(src, &(*dst)[rloc][0]);
    };
    auto STAGE_B = [&](int kt, BTile* dst) {
        #pragma unroll
        for (int i = 0; i < 2; ++i) {
            int rloc = i * 64 + w * 8;
            int row = rloc + lrow8;
            const char* src = (const char*)(attTB + (size_t)(m_base + row) * N)
                              + kt * 128 + ((lc ^ (row & 7)) * 16);
            GLOAD_LDS16(src, &(*dst)[rloc][0]);
        }
    };

    f32x4 zero4 = {0.f, 0.f, 0.f, 0.f};
    f32x4 acc[2][2];
    #pragma unroll
    for (int di = 0; di < 2; ++di)
        #pragma unroll
        for (int mj = 0; mj < 2; ++mj) acc[di][mj] = zero4;

    STAGE_A(0, &As[0]);
    STAGE_B(0, &Bs[0]);

    int buf = 0;
    for (int kt = 0; kt < 32; ++kt) {
        if (kt < 31) {
            STAGE_A(kt + 1, &As[buf ^ 1]);
            STAGE_B(kt + 1, &Bs[buf ^ 1]);
            VMCNT("3");
        } else {
            VMCNT("0");
        }
        BAR();
        __builtin_amdgcn_s_setprio(1);
        #pragma unroll
        for (int ks = 0; ks < 2; ++ks) {
            short8 af[2], bf[2];
            #pragma unroll
            for (int di = 0; di < 2; ++di) {
                int r = wd * 32 + di * 16 + l16;
                af[di] = *(const short8*)(&As[buf][r][(ks * 32 + lq * 8) ^ ((r & 7) << 3)]);
            }
            #pragma unroll
            for (int mj = 0; mj < 2; ++mj) {
                int r = wm * 32 + mj * 16 + l16;
                bf[mj] = *(const short8*)(&Bs[buf][r][(ks * 32 + lq * 8) ^ ((r & 7) << 3)]);
            }
            #pragma unroll
            for (int di = 0; di < 2; ++di)
                #pragma unroll
                for (int mj = 0; mj < 2; ++mj)
                    acc[di][mj] = MFMA(af[di], bf[mj], acc[di][mj]);
        }
        __builtin_amdgcn_s_setprio(0);
        BAR();
        buf ^= 1;
    }

    #pragma unroll
    for (int di = 0; di < 2; ++di)
        #pragma unroll
        for (int mj = 0; mj < 2; ++mj)
            #pragma unroll
            for (int rg = 0; rg < 4; ++rg) {
                int dd = d_base + wd * 32 + di * 16 + lq * 4 + rg;
                int mm = m_base + wm * 32 + mj * 16 + l16;
                size_t off = (size_t)b * ZSTRIDE + (size_t)dd * N + mm;
                out[off] = Z[off] + acc[di][mj][rg];
            }

    // fused Y epilogue: d_base==0 blocks write Y_out for their m-range
    if (d_base == 0 && tid < 128) {
        int mm = m_base + tid;
        size_t off = (size_t)b * ZSTRIDE + (size_t)256 * N + mm;
        out[off] = Z[off] + r_l[0] * accY[(size_t)b * N + mm];
    }
}

// ---------------------------------------------------------------------------
// Fallback fused kernel (round-4, known-good) if ws too small for attT
// ---------------------------------------------------------------------------
__global__ __launch_bounds__(512, 4) void fused_kernel(
    const float* __restrict__ Z, const short* __restrict__ Xt,
    const short* __restrict__ Wt, const short* __restrict__ Px,
    const short* __restrict__ Yb, const float* __restrict__ r_l,
    float* __restrict__ out)
{
    __shared__ __align__(16) short xtsA[32][256];
    __shared__ __align__(16) short xtsB[32][256];
    __shared__ __align__(16) short attA[64][36];
    __shared__ __align__(16) short attB[64][36];

    int blk = blockIdx.x;
    int b = blk & 7;
    int m_base = (blk >> 3) << 6;
    int tid = threadIdx.x;
    int w = tid >> 6, l = tid & 63;
    int l16 = l & 15, lq = l >> 4;

    const short* XtB = Xt + (size_t)b * (N * D);
    const short* WtB = Wt + (size_t)b * (N * D);
    const short* PxB = Px + (size_t)b * (D * N);
    const short* YbB = Yb + b * N;

    int mi = w >> 1;
    int nj = w & 1;

    short8 a_wt[8];
    {
        const short* ap = WtB + (size_t)(m_base + 16 * mi + l16) * D + lq * 8;
        #pragma unroll
        for (int ks = 0; ks < 8; ++ks)
            a_wt[ks] = *(const short8*)(ap + ks * 32);
    }

    f32x4 zero4 = {0.f, 0.f, 0.f, 0.f};
    f32x4 accX[2][4];
    #pragma unroll
    for (int di = 0; di < 2; ++di)
        #pragma unroll
        for (int mj = 0; mj < 4; ++mj) accX[di][mj] = zero4;

    float accY = 0.f;
    int ym = tid >> 3, yseg = tid & 7;

    auto STAGE = [&](int it, short (*dst)[256]) {
        #pragma unroll
        for (int r = 0; r < 2; ++r) {
            int row  = r * 16 + 2 * w + (l >> 5);
            int colb = ((l & 31) * 16) ^ ((row & 7) << 4);
            const char* src = (const char*)(XtB + (size_t)(it * 32 + row) * D) + colb;
            GLOAD_LDS16(src, &dst[r * 16 + 2 * w][0]);
        }
    };

    auto BODY = [&](int it, short (*xrd)[256], short (*xst)[256], short (*atw)[36]) {
        int n_base = it * 32;
        if (it + 1 < 64) STAGE(it + 1, xst);
        short8 px[2];
        #pragma unroll
        for (int di = 0; di < 2; ++di)
            px[di] = *(const short8*)(PxB + (size_t)(32 * w + 16 * di + l16) * N +
                                      n_base + lq * 8);
        short4v yv = *(const short4v*)(YbB + n_base + yseg * 4);
        f32x4 sa = zero4;
        #pragma unroll
        for (int ks = 0; ks < 8; ++ks) {
            int colsh = (ks * 32 + lq * 8) ^ ((l16 & 7) << 3);
            short8 xb = *(const short8*)(&xrd[16 * nj + l16][colsh]);
            sa = MFMA(a_wt[ks], xb, sa);
        }
        {
            int nn = 16 * nj + l16;
            #pragma unroll
            for (int rg = 0; rg < 4; ++rg) {
                int mm = 16 * mi + lq * 4 + rg;
                float v = sa[rg] > 0.f ? sa[rg] : 0.f;
                if ((m_base + mm == N - 1) && (n_base + nn == N - 1)) v = 0.f;
                atw[mm][nn] = f2bf(v);
            }
        }
        __syncthreads();
        #pragma unroll
        for (int mj = 0; mj < 4; ++mj) {
            short8 bfr = *(const short8*)(&atw[16 * mj + l16][lq * 8]);
            #pragma unroll
            for (int di = 0; di < 2; ++di)
                accX[di][mj] = MFMA(px[di], bfr, accX[di][mj]);
        }
        {
            short4v av = *(const short4v*)(&atw[ym][yseg * 4]);
            #pragma unroll
            for (int j = 0; j < 4; ++j)
                accY += bf2f(av[j]) * bf2f(yv[j]);
        }
    };

    STAGE(0, xtsA);
    __syncthreads();
    for (int it2 = 0; it2 < 32; ++it2) {
        BODY(2 * it2,     xtsA, xtsB, attA);
        BODY(2 * it2 + 1, xtsB, xtsA, attB);
    }

    #pragma unroll
    for (int di = 0; di < 2; ++di)
        #pragma unroll
        for (int mj = 0; mj < 4; ++mj)
            #pragma unroll
            for (int rg = 0; rg < 4; ++rg) {
                int dd = 32 * w + 16 * di + lq * 4 + rg;
                int mm = m_base + 16 * mj + l16;
                size_t off = (size_t)b * ZSTRIDE + (size_t)dd * N + mm;
                out[off] = Z[off] + accX[di][mj][rg];
            }
    accY += __shfl_xor(accY, 1);
    accY += __shfl_xor(accY, 2);
    accY += __shfl_xor(accY, 4);
    if (yseg == 0) {
        float r = r_l[0];
        int mm = m_base + ym;
        size_t off = (size_t)b * ZSTRIDE + (size_t)256 * N + mm;
        out[off] = Z[off] + r * accY;
    }
}

// ---------------------------------------------------------------------------
extern "C" void kernel_launch(void* const* d_in, const int* in_sizes, int n_in,
                              void* d_out, int out_size, void* d_ws, size_t ws_size,
                              hipStream_t stream) {
    const float* Z   = (const float*)d_in[0];
    const float* A_l = (const float*)d_in[1];
    const float* r_l = (const float*)d_in[2];
    const float* B_l = (const float*)d_in[3];
    const float* C_l = (const float*)d_in[4];
    float* out = (float*)d_out;

    char* ws = (char*)d_ws;
    short* G    = (short*)(ws);                  // 128 KB
    short* Ab   = (short*)(ws + 131072);         // 128 KB
    short* Xt   = (short*)(ws + 262144);         // 8 MB
    short* Wt   = (short*)(ws + 8650752);        // 8 MB
    short* Px   = (short*)(ws + 17039360);       // 8 MB
    short* Yb   = (short*)(ws + 25427968);       // 32 KB
    float* accY = (float*)(ws + 25460736);       // 64 KB
    short* attT = (short*)(ws + 25526272);       // NBCH x 8 MB

    const size_t baseNeed = 25526272;
    const size_t attSz = (size_t)N * N * 2;      // 8 MB per batch
    int NBCH = 8, nbShift = 3;
    while (NBCH > 1 && baseNeed + (size_t)NBCH * attSz > ws_size) { NBCH >>= 1; --nbShift; }
    bool decomposed = (baseNeed + (size_t)NBCH * attSz <= ws_size);

    front_kernel<<<1376, 256, 0, stream>>>(B_l, C_l, A_l, Z, G, Ab, Yb,
                                           accY, Xt, decomposed ? 1 : 0);
    prep_gemm2<<<512, 512, 0, stream>>>(Xt, G, Ab, Wt, Px);

    if (decomposed) {
        int nbMask = NBCH - 1;
        for (int c = 0; c < NB / NBCH; ++c) {
            int bBase = c * NBCH;
            scores_kernel<<<NBCH * 128, 512, 0, stream>>>(
                Xt, Wt, Yb, attT, accY, bBase, nbMask, nbShift);
            pv_kernel<<<NBCH * 64, 512, 0, stream>>>(
                Z, Px, attT, accY, r_l, out, bBase, nbMask, nbShift);
        }
    } else {
        fused_kernel<<<256, 512, 0, stream>>>(Z, Xt, Wt, Px, Yb, r_l, out);
    }
}